// Round 7
// baseline (717.869 us; speedup 1.0000x reference)
//
#include <hip/hip_runtime.h>

// GNN: N=50000 nodes, E=800000 edges, H=64, L=2.
// R7: edge/node MFMA kernels move to 32KB LDS (5 blocks/CU) via XOR-swizzled
// LDK=64 planes (pidx); Ps[src] gathers prefetched 2 phases early; launch
// fusion (conv+deg, fill+encode). Arithmetic identical to R6 (bf16x3).

#define NN 50000
#define EE 800000
#define HH 64
#define EPB 64   // rows per block; plane = EPB*64 ushorts = 8KB

typedef short short8 __attribute__((ext_vector_type(8)));
typedef short short4v __attribute__((ext_vector_type(4)));
typedef float f32x4 __attribute__((ext_vector_type(4)));

#define MFMA __builtin_amdgcn_mfma_f32_16x16x32_bf16

// wt slots (each 8192 ushorts: 4096 hi + 4096 lo, layout [f][k])
#define S_WE2   0
#define S_W1E0  1
#define S_W2E0  2
#define S_W1E1  3
#define S_W2E1  4
#define S_WN2   5
#define S_W1S0  6
#define S_W1D0  7
#define S_W1S1  8
#define S_W1D1  9
#define S_W1NX0 10
#define S_W1NA0 11
#define S_W2N0  12
#define S_W1NX1 13
#define S_W1NA1 14
#define S_W2N1  15
#define S_DW1   16
#define OFF_WE1 (17*8192)          // [f][32], K=4 padded
#define OFF_WN1 (17*8192+4096)     // [f][32], K=8 padded
#define WT_USHORTS (17*8192+8192)

// swizzled plane index: row e, feature f (0..63). 8-ushort blocks XORed by
// e&7 -> b128 row-reads spread across banks (2-way max); 16B blocks intact.
__device__ __forceinline__ int pidx(int e, int f) {
    return (e << 6) + ((((f >> 3) ^ e) & 7) << 3) + (f & 7);
}

// ---------------- bf16 helpers ----------------

__device__ __forceinline__ void split2(float x, unsigned short& h, unsigned short& l) {
    union { float f; unsigned u; } a, hf, b;
    a.f = x;
    const unsigned hb = (a.u + 0x7FFFu + ((a.u >> 16) & 1u)) >> 16;  // RNE hi
    hf.u = hb << 16;
    b.f = x - hf.f;                  // exact
    h = (unsigned short)hb;
    l = (unsigned short)(b.u >> 16); // truncated lo: err <= 2^-16 |x|
}

__device__ __forceinline__ float bf2f(unsigned short s) {
    union { unsigned u; float f; } a; a.u = ((unsigned)s) << 16; return a.f;
}

__device__ __forceinline__ float uph(unsigned u) {
    union { unsigned x; float f; } a; a.x = u & 0xFFFF0000u; return a.f;
}
__device__ __forceinline__ float upl(unsigned u) {
    union { unsigned x; float f; } a; a.x = u << 16; return a.f;
}

// A-frags for one 16-feature slice of a 64x64 weight: [chunk][plane]
__device__ __forceinline__ void load_wf(const unsigned short* __restrict__ wm,
                                        int ft, int l15, int quad, short8 (&w)[2][2]) {
#pragma unroll
    for (int c = 0; c < 2; ++c) {
        const int el = (ft * 16 + l15) * 64 + c * 32 + quad * 8;
        w[c][0] = *(const short8*)(wm + el);
        w[c][1] = *(const short8*)(wm + 4096 + el);
    }
}

// D += Ah*Bh + Al*Bh + Ah*Bl over K=64 (2 chunks)
__device__ __forceinline__ f32x4 chain6(const short8 (&w)[2][2],
                                        short8 bh0, short8 bh1,
                                        short8 bl0, short8 bl1, f32x4 a) {
    a = MFMA(w[0][0], bh0, a, 0, 0, 0);
    a = MFMA(w[1][0], bh1, a, 0, 0, 0);
    a = MFMA(w[0][1], bh0, a, 0, 0, 0);
    a = MFMA(w[1][1], bh1, a, 0, 0, 0);
    a = MFMA(w[0][0], bl0, a, 0, 0, 0);
    a = MFMA(w[1][0], bl1, a, 0, 0, 0);
    return a;
}

__device__ __forceinline__ void gemm_planes(const unsigned short* pHi, const unsigned short* pLo,
                                            const short8 (&w)[2][2], int l15, int quad,
                                            f32x4 (&acc)[4]) {
#pragma unroll
    for (int et = 0; et < 4; ++et) {
        const int e = et * 16 + l15;
        const short8 bh0 = *(const short8*)(pHi + pidx(e, quad * 8));
        const short8 bh1 = *(const short8*)(pHi + pidx(e, 32 + quad * 8));
        const short8 bl0 = *(const short8*)(pLo + pidx(e, quad * 8));
        const short8 bl1 = *(const short8*)(pLo + pidx(e, 32 + quad * 8));
        acc[et] = chain6(w, bh0, bh1, bl0, bl1, acc[et]);
    }
}

__device__ __forceinline__ void set_bias(f32x4 (&acc)[4], const float* __restrict__ b, int f0) {
    const float4 b4 = *(const float4*)(b + f0);
#pragma unroll
    for (int et = 0; et < 4; ++et) {
        acc[et][0] = b4.x; acc[et][1] = b4.y; acc[et][2] = b4.z; acc[et][3] = b4.w;
    }
}

__device__ __forceinline__ void set_zero(f32x4 (&acc)[4]) {
#pragma unroll
    for (int et = 0; et < 4; ++et)
#pragma unroll
        for (int r = 0; r < 4; ++r) acc[et][r] = 0.f;
}

__device__ __forceinline__ void relu4(f32x4 (&acc)[4]) {
#pragma unroll
    for (int et = 0; et < 4; ++et)
#pragma unroll
        for (int r = 0; r < 4; ++r) acc[et][r] = fmaxf(acc[et][r], 0.f);
}

__device__ __forceinline__ void store_split_planes(unsigned short* pHi, unsigned short* pLo,
                                                   const f32x4 (&acc)[4], int l15, int f0) {
#pragma unroll
    for (int et = 0; et < 4; ++et) {
        const int e = et * 16 + l15;
        union { unsigned short u[4]; short4v v; } h, l;
#pragma unroll
        for (int r = 0; r < 4; ++r) split2(acc[et][r], h.u[r], l.u[r]);
        *(short4v*)(pHi + pidx(e, f0)) = h.v;
        *(short4v*)(pLo + pidx(e, f0)) = l.v;
    }
}

// stage fp32 [64][64] tile -> split hi/lo planes; invalid rows zero
__device__ __forceinline__ void stage_split64(unsigned short* pHi, unsigned short* pLo,
                                              const float* g, long rowBase, int t, int nValid) {
    const int row = t >> 2, q = t & 3;
    const bool valid = row < nValid;
#pragma unroll
    for (int i = 0; i < 4; ++i) {
        const int col = q * 16 + i * 4;
        float4 v = make_float4(0.f, 0.f, 0.f, 0.f);
        if (valid) v = *(const float4*)(g + (size_t)(rowBase + row) * HH + col);
        union { unsigned short u[4]; short4v s; } h, l;
        split2(v.x, h.u[0], l.u[0]); split2(v.y, h.u[1], l.u[1]);
        split2(v.z, h.u[2], l.u[2]); split2(v.w, h.u[3], l.u[3]);
        *(short4v*)(pHi + pidx(row, col)) = h.s;
        *(short4v*)(pLo + pidx(row, col)) = l.s;
    }
}

// ---------------- fused setup: deg histogram + weight split ----------------
#define DEG_BLOCKS 3125
#define CONV_BLOCKS 288

__global__ void k_setup(const int* __restrict__ eidx, unsigned* __restrict__ deg,
                        const float* __restrict__ enc_n_w1, const float* __restrict__ enc_n_w2,
                        const float* __restrict__ enc_e_w1, const float* __restrict__ enc_e_w2,
                        const float* __restrict__ pe_w1, const float* __restrict__ pe_w2,
                        const float* __restrict__ pn_w1, const float* __restrict__ pn_w2,
                        const float* __restrict__ dw1, unsigned short* __restrict__ wt)
{
    if (blockIdx.x < DEG_BLOCKS) {
        const int e = blockIdx.x * 256 + threadIdx.x;
        if (e < EE) atomicAdd(&deg[eidx[EE + e]], 1u);
        return;
    }
    const int i = (blockIdx.x - DEG_BLOCKS) * 256 + threadIdx.x;
    if (i < 17 * 4096) {
        const int m = i >> 12, r = i & 4095;
        const int f = r & 63, k = r >> 6;
        const float* W;
        switch (m) {
            case S_WE2:   W = enc_e_w2; break;
            case S_W1E0:  W = pe_w1; break;
            case S_W2E0:  W = pe_w2; break;
            case S_W1E1:  W = pe_w1 + 192 * 64; break;
            case S_W2E1:  W = pe_w2 + 64 * 64; break;
            case S_WN2:   W = enc_n_w2; break;
            case S_W1S0:  W = pe_w1 + 64 * 64; break;
            case S_W1D0:  W = pe_w1 + 128 * 64; break;
            case S_W1S1:  W = pe_w1 + 192 * 64 + 64 * 64; break;
            case S_W1D1:  W = pe_w1 + 192 * 64 + 128 * 64; break;
            case S_W1NX0: W = pn_w1; break;
            case S_W1NA0: W = pn_w1 + 64 * 64; break;
            case S_W2N0:  W = pn_w2; break;
            case S_W1NX1: W = pn_w1 + 128 * 64; break;
            case S_W1NA1: W = pn_w1 + 128 * 64 + 64 * 64; break;
            case S_W2N1:  W = pn_w2 + 64 * 64; break;
            default:      W = dw1; break;
        }
        unsigned short h, l; split2(W[r], h, l);    // W[k*64+f]
        wt[m * 8192 + f * 64 + k] = h;
        wt[m * 8192 + 4096 + f * 64 + k] = l;
    } else if (i < 17 * 4096 + 2048) {
        const int r = i - 17 * 4096, f = r >> 5, k = r & 31;
        const float v = (k < 4) ? enc_e_w1[k * 64 + f] : 0.f;
        unsigned short h, l; split2(v, h, l);
        wt[OFF_WE1 + f * 32 + k] = h;
        wt[OFF_WE1 + 2048 + f * 32 + k] = l;
    } else if (i < 17 * 4096 + 4096) {
        const int r = i - 17 * 4096 - 2048, f = r >> 5, k = r & 31;
        const float v = (k < 8) ? enc_n_w1[k * 64 + f] : 0.f;
        unsigned short h, l; split2(v, h, l);
        wt[OFF_WN1 + f * 32 + k] = h;
        wt[OFF_WN1 + 2048 + f * 32 + k] = l;
    }
}

__global__ __launch_bounds__(1024) void k_scan(unsigned* deg, unsigned* __restrict__ off) {
    __shared__ unsigned part[1024];
    const int t = threadIdx.x;
    const int CH = (NN + 1023) / 1024;
    const int s = t * CH, e = s + CH < NN ? s + CH : NN;
    unsigned sum = 0;
    for (int i = s; i < e; ++i) sum += deg[i];
    part[t] = sum;
    __syncthreads();
    for (int d = 1; d < 1024; d <<= 1) {
        unsigned v = (t >= d) ? part[t - d] : 0u;
        __syncthreads();
        if (t >= d) part[t] += v;
        __syncthreads();
    }
    unsigned base = (t > 0) ? part[t - 1] : 0u;
    for (int i = s; i < e; ++i) {
        const unsigned d = deg[i];
        off[i] = base;
        deg[i] = base;          // reuse as fill cursor
        base += d;
    }
    if (t == 1023) off[NN] = part[1023];
}

// ---------------- fused: CSR fill + node encoder ----------------
#define FILL_BLOCKS 3125
#define ENC_BLOCKS 782

__global__ __launch_bounds__(256, 5) void k_fill_encode(
    const int* __restrict__ eidx, unsigned* __restrict__ cur,
    int* __restrict__ csr, int* __restrict__ srcs_s, int* __restrict__ dsts_s,
    const float* __restrict__ x, const unsigned short* __restrict__ wt,
    const float* __restrict__ bn1, const float* __restrict__ bn2,
    float* __restrict__ x_h, float* __restrict__ Ps, float* __restrict__ Pd)
{
    __shared__ unsigned short pXhi[EPB * 64], pXlo[EPB * 64];
    __shared__ unsigned short pHhi[EPB * 64], pHlo[EPB * 64];

    if (blockIdx.x < FILL_BLOCKS) {
        const int e = blockIdx.x * 256 + threadIdx.x;
        if (e < EE) {
            const int d = eidx[EE + e];
            const unsigned p = atomicAdd(&cur[d], 1u);
            csr[p] = e;
            srcs_s[p] = eidx[e];
            dsts_s[p] = d;
        }
        return;
    }

    const int t = threadIdx.x;
    const int lane = t & 63, ft = t >> 6;
    const int quad = lane >> 4, l15 = lane & 15;
    const int f0 = ft * 16 + quad * 4;
    const int nodeBase = (blockIdx.x - FILL_BLOCKS) * 64;
    const int nValid = min(64, NN - nodeBase);

    // stage x (8 cols) padded to 32
    {
        const int row = t >> 2, q = t & 3;
        if (q == 0) {
            float4 a0 = make_float4(0.f, 0.f, 0.f, 0.f), a1 = a0;
            if (row < nValid) {
                a0 = *(const float4*)(x + (size_t)(nodeBase + row) * 8);
                a1 = *(const float4*)(x + (size_t)(nodeBase + row) * 8 + 4);
            }
            union { unsigned short u[8]; uint4 v; } H, L;
            split2(a0.x, H.u[0], L.u[0]); split2(a0.y, H.u[1], L.u[1]);
            split2(a0.z, H.u[2], L.u[2]); split2(a0.w, H.u[3], L.u[3]);
            split2(a1.x, H.u[4], L.u[4]); split2(a1.y, H.u[5], L.u[5]);
            split2(a1.z, H.u[6], L.u[6]); split2(a1.w, H.u[7], L.u[7]);
            *(uint4*)(pXhi + pidx(row, 0)) = H.v;
            *(uint4*)(pXlo + pidx(row, 0)) = L.v;
        } else {
            const uint4 z = {0u, 0u, 0u, 0u};
            *(uint4*)(pXhi + pidx(row, q * 8)) = z;
            *(uint4*)(pXlo + pidx(row, q * 8)) = z;
        }
    }
    __syncthreads();

    f32x4 acc[4];

    // h1 = relu(x @ wn1 + bn1) -> pH
    {
        short8 wa[2];
        const int el = (ft * 16 + l15) * 32 + quad * 8;
        wa[0] = *(const short8*)(wt + OFF_WN1 + el);
        wa[1] = *(const short8*)(wt + OFF_WN1 + 2048 + el);
        set_bias(acc, bn1, f0);
#pragma unroll
        for (int et = 0; et < 4; ++et) {
            const int e = et * 16 + l15;
            const short8 bh0 = *(const short8*)(pXhi + pidx(e, quad * 8));
            const short8 bl0 = *(const short8*)(pXlo + pidx(e, quad * 8));
            f32x4 a = acc[et];
            a = MFMA(wa[0], bh0, a, 0, 0, 0);
            a = MFMA(wa[1], bh0, a, 0, 0, 0);
            a = MFMA(wa[0], bl0, a, 0, 0, 0);
            acc[et] = a;
        }
        relu4(acc);
        store_split_planes(pHhi, pHlo, acc, l15, f0);
    }
    __syncthreads();

    // x_h = h1 @ wn2 + bn2 -> global + pX
    {
        short8 w[2][2];
        load_wf(wt + S_WN2 * 8192, ft, l15, quad, w);
        set_bias(acc, bn2, f0);
        gemm_planes(pHhi, pHlo, w, l15, quad, acc);
#pragma unroll
        for (int et = 0; et < 4; ++et) {
            const int r = et * 16 + l15;
            if (r < nValid) {
                float4 v = make_float4(acc[et][0], acc[et][1], acc[et][2], acc[et][3]);
                *(float4*)(x_h + (size_t)(nodeBase + r) * HH + f0) = v;
            }
        }
        store_split_planes(pXhi, pXlo, acc, l15, f0);
    }
    __syncthreads();

    // Ps = x_h @ W1s(l0)
    {
        short8 w[2][2];
        load_wf(wt + S_W1S0 * 8192, ft, l15, quad, w);
        set_zero(acc);
        gemm_planes(pXhi, pXlo, w, l15, quad, acc);
#pragma unroll
        for (int et = 0; et < 4; ++et) {
            const int r = et * 16 + l15;
            if (r < nValid) {
                float4 v = make_float4(acc[et][0], acc[et][1], acc[et][2], acc[et][3]);
                *(float4*)(Ps + (size_t)(nodeBase + r) * HH + f0) = v;
            }
        }
    }
    // Pd = x_h @ W1d(l0)
    {
        short8 w[2][2];
        load_wf(wt + S_W1D0 * 8192, ft, l15, quad, w);
        set_zero(acc);
        gemm_planes(pXhi, pXlo, w, l15, quad, acc);
#pragma unroll
        for (int et = 0; et < 4; ++et) {
            const int r = et * 16 + l15;
            if (r < nValid) {
                float4 v = make_float4(acc[et][0], acc[et][1], acc[et][2], acc[et][3]);
                *(float4*)(Pd + (size_t)(nodeBase + r) * HH + f0) = v;
            }
        }
    }
}

// ---------------- aggregation: sorted planes -> streaming ----------------

__global__ __launch_bounds__(256, 8) void k_agg(
    const unsigned* __restrict__ off, const unsigned* __restrict__ epk,
    float* __restrict__ agg)
{
    const int wv = threadIdx.x >> 6, f = threadIdx.x & 63;
    const int n = blockIdx.x * 4 + wv;
    if (n >= NN) return;
    const unsigned s = off[n], e = off[n + 1];
    float acc = 0.f;
    unsigned j = s;
    for (; j + 4 <= e; j += 4) {
        const size_t b = (size_t)j * HH + f;
        const unsigned u0 = epk[b], u1 = epk[b + 64], u2 = epk[b + 128], u3 = epk[b + 192];
        acc += (uph(u0) + upl(u0)) + (uph(u1) + upl(u1))
             + (uph(u2) + upl(u2)) + (uph(u3) + upl(u3));
    }
    for (; j < e; ++j) {
        const unsigned u = epk[(size_t)j * HH + f];
        acc += uph(u) + upl(u);
    }
    agg[(size_t)n * HH + f] = acc;
}

// ---------------- K2: edge encoder + layer-0 edge MLP ----------------

__global__ __launch_bounds__(256, 5) void k_edge_l0(
    const float* __restrict__ eattr, const int* __restrict__ csr,
    const int* __restrict__ srcs_s, const int* __restrict__ dsts_s,
    const float* __restrict__ Ps, const float* __restrict__ Pd,
    const float* __restrict__ be1, const float* __restrict__ be2,
    const unsigned short* __restrict__ wt,
    const float* __restrict__ pb1, const float* __restrict__ pb2,
    unsigned* __restrict__ epk)
{
    __shared__ unsigned short pHhi[EPB * 64], pHlo[EPB * 64];
    __shared__ unsigned short pEhi[EPB * 64], pElo[EPB * 64];

    const int t = threadIdx.x;
    const int lane = t & 63, ft = t >> 6;
    const int quad = lane >> 4, l15 = lane & 15;
    const int f0 = ft * 16 + quad * 4;
    const long eBase = (long)blockIdx.x * EPB;

    // stage eattr (gathered via csr): k 0..3 data, 4..31 zero
    {
        const int row = t >> 2, q = t & 3;
        if (q == 0) {
            const int eid = csr[eBase + row];
            const float4 ea = *(const float4*)(eattr + (size_t)eid * 4);
            union { unsigned short u[8]; uint4 v; } H, L;
            split2(ea.x, H.u[0], L.u[0]); split2(ea.y, H.u[1], L.u[1]);
            split2(ea.z, H.u[2], L.u[2]); split2(ea.w, H.u[3], L.u[3]);
#pragma unroll
            for (int j = 4; j < 8; ++j) { H.u[j] = 0; L.u[j] = 0; }
            *(uint4*)(pHhi + pidx(row, 0)) = H.v;
            *(uint4*)(pHlo + pidx(row, 0)) = L.v;
        } else {
            const uint4 z = {0u, 0u, 0u, 0u};
            *(uint4*)(pHhi + pidx(row, q * 8)) = z;
            *(uint4*)(pHlo + pidx(row, q * 8)) = z;
        }
    }
    int srcs[4], dsts[4];
#pragma unroll
    for (int et = 0; et < 4; ++et) {
        const long p = eBase + et * 16 + l15;
        srcs[et] = srcs_s[p];
        dsts[et] = dsts_s[p];
    }
    __syncthreads();

    f32x4 acc[4];

    // phase1: h0 = relu(eattr @ We1 + be1) -> pE
    {
        short8 wa[2];
        const int el = (ft * 16 + l15) * 32 + quad * 8;
        wa[0] = *(const short8*)(wt + OFF_WE1 + el);
        wa[1] = *(const short8*)(wt + OFF_WE1 + 2048 + el);
        set_bias(acc, be1, f0);
#pragma unroll
        for (int et = 0; et < 4; ++et) {
            const int e = et * 16 + l15;
            const short8 bh0 = *(const short8*)(pHhi + pidx(e, quad * 8));
            const short8 bl0 = *(const short8*)(pHlo + pidx(e, quad * 8));
            f32x4 a = acc[et];
            a = MFMA(wa[0], bh0, a, 0, 0, 0);
            a = MFMA(wa[1], bh0, a, 0, 0, 0);
            a = MFMA(wa[0], bl0, a, 0, 0, 0);
            acc[et] = a;
        }
        relu4(acc);
        store_split_planes(pEhi, pElo, acc, l15, f0);
    }

    // prefetch random Ps[src] gathers (consumed in phase3, ~2 phases later)
    float4 gps[4];
#pragma unroll
    for (int et = 0; et < 4; ++et)
        gps[et] = *(const float4*)(Ps + (size_t)srcs[et] * HH + f0);

    __syncthreads();

    // phase2: e0 = h0 @ We2 + be2 (regs) -> pH
    f32x4 e0s[4];
    {
        short8 w[2][2];
        load_wf(wt + S_WE2 * 8192, ft, l15, quad, w);
        set_bias(acc, be2, f0);
        gemm_planes(pEhi, pElo, w, l15, quad, acc);
#pragma unroll
        for (int et = 0; et < 4; ++et) e0s[et] = acc[et];
        store_split_planes(pHhi, pHlo, acc, l15, f0);
    }
    __syncthreads();

    // phase3: t1 = relu(e0 @ W1e + Ps[src] + Pd[dst] + pb1) -> pE
    {
        short8 w[2][2];
        load_wf(wt + S_W1E0 * 8192, ft, l15, quad, w);
        set_zero(acc);
        gemm_planes(pHhi, pHlo, w, l15, quad, acc);
        const float4 b4 = *(const float4*)(pb1 + f0);
#pragma unroll
        for (int et = 0; et < 4; ++et) {
            const float4 ps = gps[et];
            const float4 pd = *(const float4*)(Pd + (size_t)dsts[et] * HH + f0);
            acc[et][0] = fmaxf(acc[et][0] + ps.x + pd.x + b4.x, 0.f);
            acc[et][1] = fmaxf(acc[et][1] + ps.y + pd.y + b4.y, 0.f);
            acc[et][2] = fmaxf(acc[et][2] + ps.z + pd.z + b4.z, 0.f);
            acc[et][3] = fmaxf(acc[et][3] + ps.w + pd.w + b4.w, 0.f);
        }
        store_split_planes(pEhi, pElo, acc, l15, f0);
    }
    __syncthreads();

    // phase4: e1 = e0(regs) + t1 @ W2e + pb2 -> pH
    {
        short8 w[2][2];
        load_wf(wt + S_W2E0 * 8192, ft, l15, quad, w);
        set_zero(acc);
        gemm_planes(pEhi, pElo, w, l15, quad, acc);
        const float4 b4 = *(const float4*)(pb2 + f0);
#pragma unroll
        for (int et = 0; et < 4; ++et) {
            acc[et][0] += e0s[et][0] + b4.x;
            acc[et][1] += e0s[et][1] + b4.y;
            acc[et][2] += e0s[et][2] + b4.z;
            acc[et][3] += e0s[et][3] + b4.w;
        }
        store_split_planes(pHhi, pHlo, acc, l15, f0);
    }
    __syncthreads();

    // pack pH -> epk (sorted positions)
    {
        const int row = t >> 2, q = t & 3;
#pragma unroll
        for (int half = 0; half < 2; ++half) {
            const int lo = pidx(row, q * 8 + half * 32);
            const long go = (eBase + row) * HH + q * 8 + half * 32;
            union { unsigned short u[8]; uint4 v; } H, L;
            H.v = *(const uint4*)(pHhi + lo);
            L.v = *(const uint4*)(pHlo + lo);
            union { unsigned u[8]; uint4 v[2]; } o;
#pragma unroll
            for (int i = 0; i < 8; ++i) o.u[i] = ((unsigned)H.u[i] << 16) | L.u[i];
            *(uint4*)(epk + go) = o.v[0];
            *(uint4*)(epk + go + 4) = o.v[1];
        }
    }
}

// ---------------- K4: layer-1 edge MLP ----------------

__global__ __launch_bounds__(256, 5) void k_edge_l1(
    const int* __restrict__ srcs_s, const int* __restrict__ dsts_s,
    const float* __restrict__ Ps, const float* __restrict__ Pd,
    const unsigned short* __restrict__ wt,
    const float* __restrict__ pb1, const float* __restrict__ pb2,
    unsigned* __restrict__ epk)
{
    __shared__ unsigned short pEhi[EPB * 64], pElo[EPB * 64];
    __shared__ unsigned short pHhi[EPB * 64], pHlo[EPB * 64];

    const int t = threadIdx.x;
    const int lane = t & 63, ft = t >> 6;
    const int quad = lane >> 4, l15 = lane & 15;
    const int f0 = ft * 16 + quad * 4;
    const long eBase = (long)blockIdx.x * EPB;

    int srcs[4], dsts[4];
#pragma unroll
    for (int et = 0; et < 4; ++et) {
        const long p = eBase + et * 16 + l15;
        srcs[et] = srcs_s[p];
        dsts[et] = dsts_s[p];
    }
    // prefetch random Ps[src] gathers (consumed after first GEMM)
    float4 gps[4];
#pragma unroll
    for (int et = 0; et < 4; ++et)
        gps[et] = *(const float4*)(Ps + (size_t)srcs[et] * HH + f0);

    // load epk -> deinterleave -> pE
    {
        const int row = t >> 2, q = t & 3;
#pragma unroll
        for (int half = 0; half < 2; ++half) {
            const int lo = pidx(row, q * 8 + half * 32);
            const long go = (eBase + row) * HH + q * 8 + half * 32;
            union { unsigned u[8]; uint4 v[2]; } in;
            in.v[0] = *(const uint4*)(epk + go);
            in.v[1] = *(const uint4*)(epk + go + 4);
            union { unsigned short u[8]; uint4 v; } H, L;
#pragma unroll
            for (int i = 0; i < 8; ++i) {
                H.u[i] = (unsigned short)(in.u[i] >> 16);
                L.u[i] = (unsigned short)(in.u[i] & 0xFFFFu);
            }
            *(uint4*)(pEhi + lo) = H.v;
            *(uint4*)(pElo + lo) = L.v;
        }
    }
    __syncthreads();

    f32x4 acc[4];

    // t1 = relu(e1 @ W1e + Ps[src] + Pd[dst] + pb1) -> pH
    {
        short8 w[2][2];
        load_wf(wt + S_W1E1 * 8192, ft, l15, quad, w);
        set_zero(acc);
        gemm_planes(pEhi, pElo, w, l15, quad, acc);
        const float4 b4 = *(const float4*)(pb1 + f0);
#pragma unroll
        for (int et = 0; et < 4; ++et) {
            const float4 ps = gps[et];
            const float4 pd = *(const float4*)(Pd + (size_t)dsts[et] * HH + f0);
            acc[et][0] = fmaxf(acc[et][0] + ps.x + pd.x + b4.x, 0.f);
            acc[et][1] = fmaxf(acc[et][1] + ps.y + pd.y + b4.y, 0.f);
            acc[et][2] = fmaxf(acc[et][2] + ps.z + pd.z + b4.z, 0.f);
            acc[et][3] = fmaxf(acc[et][3] + ps.w + pd.w + b4.w, 0.f);
        }
        store_split_planes(pHhi, pHlo, acc, l15, f0);
    }
    __syncthreads();

    // e2 = e1(pE residual, own cells) + t1 @ W2e + pb2 -> pE
    {
        short8 w[2][2];
        load_wf(wt + S_W2E1 * 8192, ft, l15, quad, w);
        set_zero(acc);
        gemm_planes(pHhi, pHlo, w, l15, quad, acc);
        const float4 b4 = *(const float4*)(pb2 + f0);
#pragma unroll
        for (int et = 0; et < 4; ++et) {
            const int e = et * 16 + l15;
            const short4v hv = *(const short4v*)(pEhi + pidx(e, f0));
            const short4v lv = *(const short4v*)(pElo + pidx(e, f0));
            acc[et][0] += bf2f((unsigned short)hv[0]) + bf2f((unsigned short)lv[0]) + b4.x;
            acc[et][1] += bf2f((unsigned short)hv[1]) + bf2f((unsigned short)lv[1]) + b4.y;
            acc[et][2] += bf2f((unsigned short)hv[2]) + bf2f((unsigned short)lv[2]) + b4.z;
            acc[et][3] += bf2f((unsigned short)hv[3]) + bf2f((unsigned short)lv[3]) + b4.w;
        }
        store_split_planes(pEhi, pElo, acc, l15, f0);   // own cells, same thread
    }
    __syncthreads();

    // pack pE -> epk
    {
        const int row = t >> 2, q = t & 3;
#pragma unroll
        for (int half = 0; half < 2; ++half) {
            const int lo = pidx(row, q * 8 + half * 32);
            const long go = (eBase + row) * HH + q * 8 + half * 32;
            union { unsigned short u[8]; uint4 v; } H, L;
            H.v = *(const uint4*)(pEhi + lo);
            L.v = *(const uint4*)(pElo + lo);
            union { unsigned u[8]; uint4 v[2]; } o;
#pragma unroll
            for (int i = 0; i < 8; ++i) o.u[i] = ((unsigned)H.u[i] << 16) | L.u[i];
            *(uint4*)(epk + go) = o.v[0];
            *(uint4*)(epk + go + 4) = o.v[1];
        }
    }
}

// ---------------- K3: node update l0 + layer-1 projections ----------------
// agg aliases Ps: stage reads agg rows before first barrier; Ps written later.

__global__ __launch_bounds__(256, 5) void k_node_l0(
    float* x_h, const float* agg, const unsigned short* __restrict__ wt,
    const float* __restrict__ nb1, const float* __restrict__ nb2,
    float* Ps, float* __restrict__ Pd)
{
    __shared__ unsigned short pXhi[EPB * 64], pXlo[EPB * 64];
    __shared__ unsigned short pAhi[EPB * 64], pAlo[EPB * 64];

    const int t = threadIdx.x;
    const int lane = t & 63, ft = t >> 6;
    const int quad = lane >> 4, l15 = lane & 15;
    const int f0 = ft * 16 + quad * 4;
    const int nodeBase = blockIdx.x * 64;
    const int nValid = min(64, NN - nodeBase);

    stage_split64(pXhi, pXlo, x_h, nodeBase, t, nValid);
    stage_split64(pAhi, pAlo, agg, nodeBase, t, nValid);
    __syncthreads();

    f32x4 acc[4];

    // t1 = relu(x_h @ W1x + agg @ W1a + nb1)
    {
        short8 w[2][2];
        load_wf(wt + S_W1NX0 * 8192, ft, l15, quad, w);
        set_bias(acc, nb1, f0);
        gemm_planes(pXhi, pXlo, w, l15, quad, acc);
        load_wf(wt + S_W1NA0 * 8192, ft, l15, quad, w);
        gemm_planes(pAhi, pAlo, w, l15, quad, acc);
        relu4(acc);
    }
    __syncthreads();                                // pA reads complete
    store_split_planes(pAhi, pAlo, acc, l15, f0);   // t1 -> pA
    __syncthreads();

    // x_h1 = x_h + t1 @ W2n + nb2 -> global + pX
    {
        short8 w[2][2];
        load_wf(wt + S_W2N0 * 8192, ft, l15, quad, w);
        set_bias(acc, nb2, f0);
        gemm_planes(pAhi, pAlo, w, l15, quad, acc);
#pragma unroll
        for (int et = 0; et < 4; ++et) {
            const int r = et * 16 + l15;
            if (r < nValid) {
                const size_t gi = (size_t)(nodeBase + r) * HH + f0;
                const float4 xr = *(const float4*)(x_h + gi);
                acc[et][0] += xr.x; acc[et][1] += xr.y;
                acc[et][2] += xr.z; acc[et][3] += xr.w;
                float4 v = make_float4(acc[et][0], acc[et][1], acc[et][2], acc[et][3]);
                *(float4*)(x_h + gi) = v;
            }
        }
        store_split_planes(pXhi, pXlo, acc, l15, f0);
    }
    __syncthreads();

    // Ps1 = x_h1 @ W1s(l1)
    {
        short8 w[2][2];
        load_wf(wt + S_W1S1 * 8192, ft, l15, quad, w);
        set_zero(acc);
        gemm_planes(pXhi, pXlo, w, l15, quad, acc);
#pragma unroll
        for (int et = 0; et < 4; ++et) {
            const int r = et * 16 + l15;
            if (r < nValid) {
                float4 v = make_float4(acc[et][0], acc[et][1], acc[et][2], acc[et][3]);
                *(float4*)(Ps + (size_t)(nodeBase + r) * HH + f0) = v;
            }
        }
    }
    // Pd1 = x_h1 @ W1d(l1)
    {
        short8 w[2][2];
        load_wf(wt + S_W1D1 * 8192, ft, l15, quad, w);
        set_zero(acc);
        gemm_planes(pXhi, pXlo, w, l15, quad, acc);
#pragma unroll
        for (int et = 0; et < 4; ++et) {
            const int r = et * 16 + l15;
            if (r < nValid) {
                float4 v = make_float4(acc[et][0], acc[et][1], acc[et][2], acc[et][3]);
                *(float4*)(Pd + (size_t)(nodeBase + r) * HH + f0) = v;
            }
        }
    }
}

// ---------------- K5: node update l1 + decoder ----------------

__global__ __launch_bounds__(256, 4) void k_node_l1_dec(
    const float* x_h, const float* agg, const unsigned short* __restrict__ wt,
    const float* __restrict__ nb1, const float* __restrict__ nb2,
    const float* __restrict__ db1, const float* __restrict__ dw2,
    const float* __restrict__ db2, float* __restrict__ out)
{
    __shared__ unsigned short pXhi[EPB * 64], pXlo[EPB * 64];
    __shared__ unsigned short pAhi[EPB * 64], pAlo[EPB * 64];
    __shared__ float sW2[64 * 6];

    const int t = threadIdx.x;
    const int lane = t & 63, ft = t >> 6;
    const int quad = lane >> 4, l15 = lane & 15;
    const int f0 = ft * 16 + quad * 4;
    const int nodeBase = blockIdx.x * 64;
    const int nValid = min(64, NN - nodeBase);

    stage_split64(pXhi, pXlo, x_h, nodeBase, t, nValid);
    stage_split64(pAhi, pAlo, agg, nodeBase, t, nValid);
    if (t < 192) {
        sW2[t] = dw2[t];
        sW2[t + 192] = dw2[t + 192];
    }
    __syncthreads();

    f32x4 acc[4];

    // t1 = relu(x_h @ W1x + agg @ W1a + nb1)
    {
        short8 w[2][2];
        load_wf(wt + S_W1NX1 * 8192, ft, l15, quad, w);
        set_bias(acc, nb1, f0);
        gemm_planes(pXhi, pXlo, w, l15, quad, acc);
        load_wf(wt + S_W1NA1 * 8192, ft, l15, quad, w);
        gemm_planes(pAhi, pAlo, w, l15, quad, acc);
        relu4(acc);
    }
    __syncthreads();
    store_split_planes(pAhi, pAlo, acc, l15, f0);   // t1 -> pA
    __syncthreads();

    // x_h2 = x_h + t1 @ W2n + nb2 -> pX
    {
        short8 w[2][2];
        load_wf(wt + S_W2N1 * 8192, ft, l15, quad, w);
        set_bias(acc, nb2, f0);
        gemm_planes(pAhi, pAlo, w, l15, quad, acc);
#pragma unroll
        for (int et = 0; et < 4; ++et) {
            const int r = et * 16 + l15;
            if (r < nValid) {
                const float4 xr = *(const float4*)(x_h + (size_t)(nodeBase + r) * HH + f0);
                acc[et][0] += xr.x; acc[et][1] += xr.y;
                acc[et][2] += xr.z; acc[et][3] += xr.w;
            }
        }
        store_split_planes(pXhi, pXlo, acc, l15, f0);
    }
    __syncthreads();

    // d1 = relu(x_h2 @ dec_w1 + db1) -> pA
    {
        short8 w[2][2];
        load_wf(wt + S_DW1 * 8192, ft, l15, quad, w);
        set_bias(acc, db1, f0);
        gemm_planes(pXhi, pXlo, w, l15, quad, acc);
        relu4(acc);
        store_split_planes(pAhi, pAlo, acc, l15, f0);
    }
    __syncthreads();

    // out = d1 @ dec_w2 + db2  (64 nodes x 6)
    if (t < 64 && t < nValid) {
        float o[6];
#pragma unroll
        for (int c = 0; c < 6; ++c) o[c] = db2[c];
#pragma unroll 8
        for (int k = 0; k < 64; ++k) {
            const int pi = pidx(t, k);
            const float a = bf2f(pAhi[pi]) + bf2f(pAlo[pi]);
#pragma unroll
            for (int c = 0; c < 6; ++c) o[c] = fmaf(a, sW2[k * 6 + c], o[c]);
        }
        float* op = out + (size_t)(nodeBase + t) * 6;
#pragma unroll
        for (int c = 0; c < 6; ++c) op[c] = o[c];
    }
}

// ---------------- launcher ----------------

extern "C" void kernel_launch(void* const* d_in, const int* in_sizes, int n_in,
                              void* d_out, int out_size, void* d_ws, size_t ws_size,
                              hipStream_t stream) {
    const float* x        = (const float*)d_in[0];
    const float* eattr    = (const float*)d_in[1];
    const int*   eidx     = (const int*)d_in[2];
    const float* enc_n_w1 = (const float*)d_in[3];
    const float* enc_n_b1 = (const float*)d_in[4];
    const float* enc_n_w2 = (const float*)d_in[5];
    const float* enc_n_b2 = (const float*)d_in[6];
    const float* enc_e_w1 = (const float*)d_in[7];
    const float* enc_e_b1 = (const float*)d_in[8];
    const float* enc_e_w2 = (const float*)d_in[9];
    const float* enc_e_b2 = (const float*)d_in[10];
    const float* pe_w1    = (const float*)d_in[11];  // [2,192,64]
    const float* pe_b1    = (const float*)d_in[12];  // [2,64]
    const float* pe_w2    = (const float*)d_in[13];  // [2,64,64]
    const float* pe_b2    = (const float*)d_in[14];  // [2,64]
    const float* pn_w1    = (const float*)d_in[15];  // [2,128,64]
    const float* pn_b1    = (const float*)d_in[16];
    const float* pn_w2    = (const float*)d_in[17];  // [2,64,64]
    const float* pn_b2    = (const float*)d_in[18];
    const float* dw1      = (const float*)d_in[19];
    const float* db1      = (const float*)d_in[20];
    const float* dw2      = (const float*)d_in[21];
    const float* db2      = (const float*)d_in[22];
    float* out = (float*)d_out;

    // ws: x_h | Ps(=agg) | Pd | epk | off | deg | csr | srcs_s | dsts_s | wt
    const size_t NNHH = (size_t)NN * HH;
    float* ws  = (float*)d_ws;
    float* x_h = ws;
    float* Ps  = ws + NNHH;
    float* agg = Ps;                       // aliased
    float* Pd  = ws + 2 * NNHH;
    unsigned* epk = (unsigned*)(ws + 3 * NNHH);           // EE*HH uints
    unsigned* off = epk + (size_t)EE * HH;                // NN+1
    unsigned* deg = off + (NN + 1);                       // NN, reused as cursor
    int* csr    = (int*)(deg + NN);                       // EE
    int* srcs_s = csr + EE;                               // EE
    int* dsts_s = srcs_s + EE;                            // EE
    unsigned short* wt = (unsigned short*)(dsts_s + EE);  // WT_USHORTS

    const int edgeBlocks = EE / EPB;         // 12500

    hipMemsetAsync(deg, 0, (size_t)NN * sizeof(unsigned), stream);

    k_setup<<<DEG_BLOCKS + CONV_BLOCKS, 256, 0, stream>>>(
        eidx, deg,
        enc_n_w1, enc_n_w2, enc_e_w1, enc_e_w2,
        pe_w1, pe_w2, pn_w1, pn_w2, dw1, wt);

    k_scan<<<1, 1024, 0, stream>>>(deg, off);

    k_fill_encode<<<FILL_BLOCKS + ENC_BLOCKS, 256, 0, stream>>>(
        eidx, deg, csr, srcs_s, dsts_s,
        x, wt, enc_n_b1, enc_n_b2, x_h, Ps, Pd);

    k_edge_l0<<<edgeBlocks, 256, 0, stream>>>(
        eattr, csr, srcs_s, dsts_s, Ps, Pd,
        enc_e_b1, enc_e_b2, wt, pe_b1, pe_b2, epk);

    k_agg<<<(NN + 3) / 4, 256, 0, stream>>>(off, epk, agg);

    k_node_l0<<<(NN + 63) / 64, 256, 0, stream>>>(
        x_h, agg, wt, pn_b1, pn_b2, Ps, Pd);

    k_edge_l1<<<edgeBlocks, 256, 0, stream>>>(
        srcs_s, dsts_s, Ps, Pd, wt, pe_b1 + 64, pe_b2 + 64, epk);

    k_agg<<<(NN + 3) / 4, 256, 0, stream>>>(off, epk, agg);

    k_node_l1_dec<<<(NN + 63) / 64, 256, 0, stream>>>(
        x_h, agg, wt, pn_b1 + 64, pn_b2 + 64,
        db1, dw2, db2, out);
}

// Round 8
// 697.790 us; speedup vs baseline: 1.0288x; 1.0288x over previous
//
#include <hip/hip_runtime.h>

// GNN: N=50000 nodes, E=800000 edges, H=64, L=2.
// R8: revert R7's swizzle/prefetch (R6 edge config was best); keep launch
// fusions; fuse aggregation INTO node kernels (each 64-node block streams its
// contiguous sorted epk rows straight into LDS planes) -> no agg buffer, no
// k_agg dispatches, no Ps aliasing. Node residuals from planes (hi+lo).

#define NN 50000
#define EE 800000
#define HH 64
#define LDK 72   // bf16 plane leading dim (144 B row)
#define EPB 64   // rows per block

typedef short short8 __attribute__((ext_vector_type(8)));
typedef short short4v __attribute__((ext_vector_type(4)));
typedef float f32x4 __attribute__((ext_vector_type(4)));

#define MFMA __builtin_amdgcn_mfma_f32_16x16x32_bf16

// wt slots (each 8192 ushorts: 4096 hi + 4096 lo, layout [f][k])
#define S_WE2   0
#define S_W1E0  1
#define S_W2E0  2
#define S_W1E1  3
#define S_W2E1  4
#define S_WN2   5
#define S_W1S0  6
#define S_W1D0  7
#define S_W1S1  8
#define S_W1D1  9
#define S_W1NX0 10
#define S_W1NA0 11
#define S_W2N0  12
#define S_W1NX1 13
#define S_W1NA1 14
#define S_W2N1  15
#define S_DW1   16
#define OFF_WE1 (17*8192)          // [f][32], K=4 padded
#define OFF_WN1 (17*8192+4096)     // [f][32], K=8 padded
#define WT_USHORTS (17*8192+8192)

// ---------------- bf16 helpers ----------------

__device__ __forceinline__ void split2(float x, unsigned short& h, unsigned short& l) {
    union { float f; unsigned u; } a, hf, b;
    a.f = x;
    const unsigned hb = (a.u + 0x7FFFu + ((a.u >> 16) & 1u)) >> 16;  // RNE hi
    hf.u = hb << 16;
    b.f = x - hf.f;                  // exact
    h = (unsigned short)hb;
    l = (unsigned short)(b.u >> 16); // truncated lo
}

__device__ __forceinline__ float bf2f(unsigned short s) {
    union { unsigned u; float f; } a; a.u = ((unsigned)s) << 16; return a.f;
}

__device__ __forceinline__ float uph(unsigned u) {
    union { unsigned x; float f; } a; a.x = u & 0xFFFF0000u; return a.f;
}
__device__ __forceinline__ float upl(unsigned u) {
    union { unsigned x; float f; } a; a.x = u << 16; return a.f;
}

// A-frags for one 16-feature slice of a 64x64 weight: [chunk][plane]
__device__ __forceinline__ void load_wf(const unsigned short* __restrict__ wm,
                                        int ft, int l15, int quad, short8 (&w)[2][2]) {
#pragma unroll
    for (int c = 0; c < 2; ++c) {
        const int el = (ft * 16 + l15) * 64 + c * 32 + quad * 8;
        w[c][0] = *(const short8*)(wm + el);
        w[c][1] = *(const short8*)(wm + 4096 + el);
    }
}

// D += Ah*Bh + Al*Bh + Ah*Bl over K=64 (2 chunks)
__device__ __forceinline__ f32x4 chain6(const short8 (&w)[2][2],
                                        short8 bh0, short8 bh1,
                                        short8 bl0, short8 bl1, f32x4 a) {
    a = MFMA(w[0][0], bh0, a, 0, 0, 0);
    a = MFMA(w[1][0], bh1, a, 0, 0, 0);
    a = MFMA(w[0][1], bh0, a, 0, 0, 0);
    a = MFMA(w[1][1], bh1, a, 0, 0, 0);
    a = MFMA(w[0][0], bl0, a, 0, 0, 0);
    a = MFMA(w[1][0], bl1, a, 0, 0, 0);
    return a;
}

__device__ __forceinline__ void gemm_planes(const unsigned short* pHi, const unsigned short* pLo,
                                            const short8 (&w)[2][2], int l15, int quad,
                                            f32x4 (&acc)[4]) {
#pragma unroll
    for (int et = 0; et < 4; ++et) {
        const int e = et * 16 + l15;
        const short8 bh0 = *(const short8*)(pHi + e * LDK + quad * 8);
        const short8 bh1 = *(const short8*)(pHi + e * LDK + 32 + quad * 8);
        const short8 bl0 = *(const short8*)(pLo + e * LDK + quad * 8);
        const short8 bl1 = *(const short8*)(pLo + e * LDK + 32 + quad * 8);
        acc[et] = chain6(w, bh0, bh1, bl0, bl1, acc[et]);
    }
}

__device__ __forceinline__ void set_bias(f32x4 (&acc)[4], const float* __restrict__ b, int f0) {
    const float4 b4 = *(const float4*)(b + f0);
#pragma unroll
    for (int et = 0; et < 4; ++et) {
        acc[et][0] = b4.x; acc[et][1] = b4.y; acc[et][2] = b4.z; acc[et][3] = b4.w;
    }
}

__device__ __forceinline__ void set_zero(f32x4 (&acc)[4]) {
#pragma unroll
    for (int et = 0; et < 4; ++et)
#pragma unroll
        for (int r = 0; r < 4; ++r) acc[et][r] = 0.f;
}

__device__ __forceinline__ void relu4(f32x4 (&acc)[4]) {
#pragma unroll
    for (int et = 0; et < 4; ++et)
#pragma unroll
        for (int r = 0; r < 4; ++r) acc[et][r] = fmaxf(acc[et][r], 0.f);
}

__device__ __forceinline__ void store_split_planes(unsigned short* pHi, unsigned short* pLo,
                                                   const f32x4 (&acc)[4], int l15, int f0) {
#pragma unroll
    for (int et = 0; et < 4; ++et) {
        const int e = et * 16 + l15;
        union { unsigned short u[4]; short4v v; } h, l;
#pragma unroll
        for (int r = 0; r < 4; ++r) split2(acc[et][r], h.u[r], l.u[r]);
        *(short4v*)(pHi + e * LDK + f0) = h.v;
        *(short4v*)(pLo + e * LDK + f0) = l.v;
    }
}

// stage fp32 [64][64] tile -> split hi/lo planes; invalid rows zero
__device__ __forceinline__ void stage_split64(unsigned short* pHi, unsigned short* pLo,
                                              const float* g, long rowBase, int t, int nValid) {
    const int row = t >> 2, q = t & 3;
    const bool valid = row < nValid;
#pragma unroll
    for (int i = 0; i < 4; ++i) {
        const int col = q * 16 + i * 4;
        float4 v = make_float4(0.f, 0.f, 0.f, 0.f);
        if (valid) v = *(const float4*)(g + (size_t)(rowBase + row) * HH + col);
        union { unsigned short u[4]; short4v s; } h, l;
        split2(v.x, h.u[0], l.u[0]); split2(v.y, h.u[1], l.u[1]);
        split2(v.z, h.u[2], l.u[2]); split2(v.w, h.u[3], l.u[3]);
        *(short4v*)(pHi + row * LDK + col) = h.s;
        *(short4v*)(pLo + row * LDK + col) = l.s;
    }
}

// aggregate this block's 64 nodes from sorted epk rows -> pA planes
__device__ __forceinline__ void agg_to_planes(const unsigned* __restrict__ off,
                                              const unsigned* __restrict__ epk,
                                              unsigned short* pAhi, unsigned short* pAlo,
                                              int nodeBase, int t) {
    const int wv = t >> 6, f = t & 63;
#pragma unroll 1
    for (int i = 0; i < 16; ++i) {
        const int r = wv * 16 + i;
        const int n = nodeBase + r;
        float acc = 0.f;
        if (n < NN) {
            const unsigned s = off[n], e = off[n + 1];
            unsigned j = s;
            for (; j + 4 <= e; j += 4) {
                const size_t b = (size_t)j * HH + f;
                const unsigned u0 = epk[b], u1 = epk[b + 64];
                const unsigned u2 = epk[b + 128], u3 = epk[b + 192];
                acc += (uph(u0) + upl(u0)) + (uph(u1) + upl(u1))
                     + (uph(u2) + upl(u2)) + (uph(u3) + upl(u3));
            }
            for (; j < e; ++j) {
                const unsigned u = epk[(size_t)j * HH + f];
                acc += uph(u) + upl(u);
            }
        }
        unsigned short h, l; split2(acc, h, l);
        pAhi[r * LDK + f] = h;
        pAlo[r * LDK + f] = l;
    }
}

// ---------------- fused setup: deg histogram + weight split ----------------
#define DEG_BLOCKS 3125
#define CONV_BLOCKS 288

__global__ void k_setup(const int* __restrict__ eidx, unsigned* __restrict__ deg,
                        const float* __restrict__ enc_n_w1, const float* __restrict__ enc_n_w2,
                        const float* __restrict__ enc_e_w1, const float* __restrict__ enc_e_w2,
                        const float* __restrict__ pe_w1, const float* __restrict__ pe_w2,
                        const float* __restrict__ pn_w1, const float* __restrict__ pn_w2,
                        const float* __restrict__ dw1, unsigned short* __restrict__ wt)
{
    if (blockIdx.x < DEG_BLOCKS) {
        const int e = blockIdx.x * 256 + threadIdx.x;
        if (e < EE) atomicAdd(&deg[eidx[EE + e]], 1u);
        return;
    }
    const int i = (blockIdx.x - DEG_BLOCKS) * 256 + threadIdx.x;
    if (i < 17 * 4096) {
        const int m = i >> 12, r = i & 4095;
        const int f = r & 63, k = r >> 6;
        const float* W;
        switch (m) {
            case S_WE2:   W = enc_e_w2; break;
            case S_W1E0:  W = pe_w1; break;
            case S_W2E0:  W = pe_w2; break;
            case S_W1E1:  W = pe_w1 + 192 * 64; break;
            case S_W2E1:  W = pe_w2 + 64 * 64; break;
            case S_WN2:   W = enc_n_w2; break;
            case S_W1S0:  W = pe_w1 + 64 * 64; break;
            case S_W1D0:  W = pe_w1 + 128 * 64; break;
            case S_W1S1:  W = pe_w1 + 192 * 64 + 64 * 64; break;
            case S_W1D1:  W = pe_w1 + 192 * 64 + 128 * 64; break;
            case S_W1NX0: W = pn_w1; break;
            case S_W1NA0: W = pn_w1 + 64 * 64; break;
            case S_W2N0:  W = pn_w2; break;
            case S_W1NX1: W = pn_w1 + 128 * 64; break;
            case S_W1NA1: W = pn_w1 + 128 * 64 + 64 * 64; break;
            case S_W2N1:  W = pn_w2 + 64 * 64; break;
            default:      W = dw1; break;
        }
        unsigned short h, l; split2(W[r], h, l);    // W[k*64+f]
        wt[m * 8192 + f * 64 + k] = h;
        wt[m * 8192 + 4096 + f * 64 + k] = l;
    } else if (i < 17 * 4096 + 2048) {
        const int r = i - 17 * 4096, f = r >> 5, k = r & 31;
        const float v = (k < 4) ? enc_e_w1[k * 64 + f] : 0.f;
        unsigned short h, l; split2(v, h, l);
        wt[OFF_WE1 + f * 32 + k] = h;
        wt[OFF_WE1 + 2048 + f * 32 + k] = l;
    } else if (i < 17 * 4096 + 4096) {
        const int r = i - 17 * 4096 - 2048, f = r >> 5, k = r & 31;
        const float v = (k < 8) ? enc_n_w1[k * 64 + f] : 0.f;
        unsigned short h, l; split2(v, h, l);
        wt[OFF_WN1 + f * 32 + k] = h;
        wt[OFF_WN1 + 2048 + f * 32 + k] = l;
    }
}

__global__ __launch_bounds__(1024) void k_scan(unsigned* deg, unsigned* __restrict__ off) {
    __shared__ unsigned part[1024];
    const int t = threadIdx.x;
    const int CH = (NN + 1023) / 1024;
    const int s = t * CH, e = s + CH < NN ? s + CH : NN;
    unsigned sum = 0;
    for (int i = s; i < e; ++i) sum += deg[i];
    part[t] = sum;
    __syncthreads();
    for (int d = 1; d < 1024; d <<= 1) {
        unsigned v = (t >= d) ? part[t - d] : 0u;
        __syncthreads();
        if (t >= d) part[t] += v;
        __syncthreads();
    }
    unsigned base = (t > 0) ? part[t - 1] : 0u;
    for (int i = s; i < e; ++i) {
        const unsigned d = deg[i];
        off[i] = base;
        deg[i] = base;          // reuse as fill cursor
        base += d;
    }
    if (t == 1023) off[NN] = part[1023];
}

// ---------------- fused: CSR fill + node encoder ----------------
#define FILL_BLOCKS 3125
#define ENC_BLOCKS 782

__global__ __launch_bounds__(256, 4) void k_fill_encode(
    const int* __restrict__ eidx, unsigned* __restrict__ cur,
    int* __restrict__ csr, int* __restrict__ srcs_s, int* __restrict__ dsts_s,
    const float* __restrict__ x, const unsigned short* __restrict__ wt,
    const float* __restrict__ bn1, const float* __restrict__ bn2,
    float* __restrict__ x_h, float* __restrict__ Ps, float* __restrict__ Pd)
{
    __shared__ unsigned short pXhi[EPB * LDK], pXlo[EPB * LDK];
    __shared__ unsigned short pHhi[EPB * LDK], pHlo[EPB * LDK];

    if (blockIdx.x < FILL_BLOCKS) {
        const int e = blockIdx.x * 256 + threadIdx.x;
        if (e < EE) {
            const int d = eidx[EE + e];
            const unsigned p = atomicAdd(&cur[d], 1u);
            csr[p] = e;
            srcs_s[p] = eidx[e];
            dsts_s[p] = d;
        }
        return;
    }

    const int t = threadIdx.x;
    const int lane = t & 63, ft = t >> 6;
    const int quad = lane >> 4, l15 = lane & 15;
    const int f0 = ft * 16 + quad * 4;
    const int nodeBase = (blockIdx.x - FILL_BLOCKS) * 64;
    const int nValid = min(64, NN - nodeBase);

    // stage x (8 cols) padded to 32
    {
        const int row = t >> 2, q = t & 3;
        if (q == 0) {
            float4 a0 = make_float4(0.f, 0.f, 0.f, 0.f), a1 = a0;
            if (row < nValid) {
                a0 = *(const float4*)(x + (size_t)(nodeBase + row) * 8);
                a1 = *(const float4*)(x + (size_t)(nodeBase + row) * 8 + 4);
            }
            union { unsigned short u[8]; uint4 v; } H, L;
            split2(a0.x, H.u[0], L.u[0]); split2(a0.y, H.u[1], L.u[1]);
            split2(a0.z, H.u[2], L.u[2]); split2(a0.w, H.u[3], L.u[3]);
            split2(a1.x, H.u[4], L.u[4]); split2(a1.y, H.u[5], L.u[5]);
            split2(a1.z, H.u[6], L.u[6]); split2(a1.w, H.u[7], L.u[7]);
            *(uint4*)(pXhi + row * LDK) = H.v;
            *(uint4*)(pXlo + row * LDK) = L.v;
        } else {
            const uint4 z = {0u, 0u, 0u, 0u};
            *(uint4*)(pXhi + row * LDK + q * 8) = z;
            *(uint4*)(pXlo + row * LDK + q * 8) = z;
        }
    }
    __syncthreads();

    f32x4 acc[4];

    // h1 = relu(x @ wn1 + bn1) -> pH
    {
        short8 wa[2];
        const int el = (ft * 16 + l15) * 32 + quad * 8;
        wa[0] = *(const short8*)(wt + OFF_WN1 + el);
        wa[1] = *(const short8*)(wt + OFF_WN1 + 2048 + el);
        set_bias(acc, bn1, f0);
#pragma unroll
        for (int et = 0; et < 4; ++et) {
            const int e = et * 16 + l15;
            const short8 bh0 = *(const short8*)(pXhi + e * LDK + quad * 8);
            const short8 bl0 = *(const short8*)(pXlo + e * LDK + quad * 8);
            f32x4 a = acc[et];
            a = MFMA(wa[0], bh0, a, 0, 0, 0);
            a = MFMA(wa[1], bh0, a, 0, 0, 0);
            a = MFMA(wa[0], bl0, a, 0, 0, 0);
            acc[et] = a;
        }
        relu4(acc);
        store_split_planes(pHhi, pHlo, acc, l15, f0);
    }
    __syncthreads();

    // x_h = h1 @ wn2 + bn2 -> global + pX
    {
        short8 w[2][2];
        load_wf(wt + S_WN2 * 8192, ft, l15, quad, w);
        set_bias(acc, bn2, f0);
        gemm_planes(pHhi, pHlo, w, l15, quad, acc);
#pragma unroll
        for (int et = 0; et < 4; ++et) {
            const int r = et * 16 + l15;
            if (r < nValid) {
                float4 v = make_float4(acc[et][0], acc[et][1], acc[et][2], acc[et][3]);
                *(float4*)(x_h + (size_t)(nodeBase + r) * HH + f0) = v;
            }
        }
        store_split_planes(pXhi, pXlo, acc, l15, f0);
    }
    __syncthreads();

    // Ps = x_h @ W1s(l0)
    {
        short8 w[2][2];
        load_wf(wt + S_W1S0 * 8192, ft, l15, quad, w);
        set_zero(acc);
        gemm_planes(pXhi, pXlo, w, l15, quad, acc);
#pragma unroll
        for (int et = 0; et < 4; ++et) {
            const int r = et * 16 + l15;
            if (r < nValid) {
                float4 v = make_float4(acc[et][0], acc[et][1], acc[et][2], acc[et][3]);
                *(float4*)(Ps + (size_t)(nodeBase + r) * HH + f0) = v;
            }
        }
    }
    // Pd = x_h @ W1d(l0)  (read-only on planes)
    {
        short8 w[2][2];
        load_wf(wt + S_W1D0 * 8192, ft, l15, quad, w);
        set_zero(acc);
        gemm_planes(pXhi, pXlo, w, l15, quad, acc);
#pragma unroll
        for (int et = 0; et < 4; ++et) {
            const int r = et * 16 + l15;
            if (r < nValid) {
                float4 v = make_float4(acc[et][0], acc[et][1], acc[et][2], acc[et][3]);
                *(float4*)(Pd + (size_t)(nodeBase + r) * HH + f0) = v;
            }
        }
    }
}

// ---------------- K2: edge encoder + layer-0 edge MLP ----------------

__global__ __launch_bounds__(256, 4) void k_edge_l0(
    const float* __restrict__ eattr, const int* __restrict__ csr,
    const int* __restrict__ srcs_s, const int* __restrict__ dsts_s,
    const float* __restrict__ Ps, const float* __restrict__ Pd,
    const float* __restrict__ be1, const float* __restrict__ be2,
    const unsigned short* __restrict__ wt,
    const float* __restrict__ pb1, const float* __restrict__ pb2,
    unsigned* __restrict__ epk)
{
    __shared__ unsigned short pHhi[EPB * LDK], pHlo[EPB * LDK];
    __shared__ unsigned short pEhi[EPB * LDK], pElo[EPB * LDK];

    const int t = threadIdx.x;
    const int lane = t & 63, ft = t >> 6;
    const int quad = lane >> 4, l15 = lane & 15;
    const int f0 = ft * 16 + quad * 4;
    const long eBase = (long)blockIdx.x * EPB;

    // stage eattr (gathered via csr): k 0..3 data, 4..31 zero
    {
        const int row = t >> 2, q = t & 3;
        if (q == 0) {
            const int eid = csr[eBase + row];
            const float4 ea = *(const float4*)(eattr + (size_t)eid * 4);
            union { unsigned short u[8]; uint4 v; } H, L;
            split2(ea.x, H.u[0], L.u[0]); split2(ea.y, H.u[1], L.u[1]);
            split2(ea.z, H.u[2], L.u[2]); split2(ea.w, H.u[3], L.u[3]);
#pragma unroll
            for (int j = 4; j < 8; ++j) { H.u[j] = 0; L.u[j] = 0; }
            *(uint4*)(pHhi + row * LDK) = H.v;
            *(uint4*)(pHlo + row * LDK) = L.v;
        } else {
            const uint4 z = {0u, 0u, 0u, 0u};
            *(uint4*)(pHhi + row * LDK + q * 8) = z;
            *(uint4*)(pHlo + row * LDK + q * 8) = z;
        }
    }
    int srcs[4], dsts[4];
#pragma unroll
    for (int et = 0; et < 4; ++et) {
        const long p = eBase + et * 16 + l15;
        srcs[et] = srcs_s[p];
        dsts[et] = dsts_s[p];
    }
    __syncthreads();

    f32x4 acc[4];

    // phase1: h0 = relu(eattr @ We1 + be1) -> pE
    {
        short8 wa[2];
        const int el = (ft * 16 + l15) * 32 + quad * 8;
        wa[0] = *(const short8*)(wt + OFF_WE1 + el);
        wa[1] = *(const short8*)(wt + OFF_WE1 + 2048 + el);
        set_bias(acc, be1, f0);
#pragma unroll
        for (int et = 0; et < 4; ++et) {
            const int e = et * 16 + l15;
            const short8 bh0 = *(const short8*)(pHhi + e * LDK + quad * 8);
            const short8 bl0 = *(const short8*)(pHlo + e * LDK + quad * 8);
            f32x4 a = acc[et];
            a = MFMA(wa[0], bh0, a, 0, 0, 0);
            a = MFMA(wa[1], bh0, a, 0, 0, 0);
            a = MFMA(wa[0], bl0, a, 0, 0, 0);
            acc[et] = a;
        }
        relu4(acc);
        store_split_planes(pEhi, pElo, acc, l15, f0);
    }
    __syncthreads();

    // phase2: e0 = h0 @ We2 + be2 (regs) -> pH
    f32x4 e0s[4];
    {
        short8 w[2][2];
        load_wf(wt + S_WE2 * 8192, ft, l15, quad, w);
        set_bias(acc, be2, f0);
        gemm_planes(pEhi, pElo, w, l15, quad, acc);
#pragma unroll
        for (int et = 0; et < 4; ++et) e0s[et] = acc[et];
        store_split_planes(pHhi, pHlo, acc, l15, f0);
    }
    __syncthreads();

    // phase3: t1 = relu(e0 @ W1e + Ps[src] + Pd[dst] + pb1) -> pE
    {
        short8 w[2][2];
        load_wf(wt + S_W1E0 * 8192, ft, l15, quad, w);
        set_zero(acc);
        gemm_planes(pHhi, pHlo, w, l15, quad, acc);
        const float4 b4 = *(const float4*)(pb1 + f0);
#pragma unroll
        for (int et = 0; et < 4; ++et) {
            const float4 ps = *(const float4*)(Ps + (size_t)srcs[et] * HH + f0);
            const float4 pd = *(const float4*)(Pd + (size_t)dsts[et] * HH + f0);
            acc[et][0] = fmaxf(acc[et][0] + ps.x + pd.x + b4.x, 0.f);
            acc[et][1] = fmaxf(acc[et][1] + ps.y + pd.y + b4.y, 0.f);
            acc[et][2] = fmaxf(acc[et][2] + ps.z + pd.z + b4.z, 0.f);
            acc[et][3] = fmaxf(acc[et][3] + ps.w + pd.w + b4.w, 0.f);
        }
        store_split_planes(pEhi, pElo, acc, l15, f0);
    }
    __syncthreads();

    // phase4: e1 = e0(regs) + t1 @ W2e + pb2 -> pH
    {
        short8 w[2][2];
        load_wf(wt + S_W2E0 * 8192, ft, l15, quad, w);
        set_zero(acc);
        gemm_planes(pEhi, pElo, w, l15, quad, acc);
        const float4 b4 = *(const float4*)(pb2 + f0);
#pragma unroll
        for (int et = 0; et < 4; ++et) {
            acc[et][0] += e0s[et][0] + b4.x;
            acc[et][1] += e0s[et][1] + b4.y;
            acc[et][2] += e0s[et][2] + b4.z;
            acc[et][3] += e0s[et][3] + b4.w;
        }
        store_split_planes(pHhi, pHlo, acc, l15, f0);
    }
    __syncthreads();

    // pack pH -> epk (sorted positions)
    {
        const int row = t >> 2, q = t & 3;
#pragma unroll
        for (int half = 0; half < 2; ++half) {
            const int lo = row * LDK + q * 8 + half * 32;
            const long go = (eBase + row) * HH + q * 8 + half * 32;
            union { unsigned short u[8]; uint4 v; } H, L;
            H.v = *(const uint4*)(pHhi + lo);
            L.v = *(const uint4*)(pHlo + lo);
            union { unsigned u[8]; uint4 v[2]; } o;
#pragma unroll
            for (int i = 0; i < 8; ++i) o.u[i] = ((unsigned)H.u[i] << 16) | L.u[i];
            *(uint4*)(epk + go) = o.v[0];
            *(uint4*)(epk + go + 4) = o.v[1];
        }
    }
}

// ---------------- K4: layer-1 edge MLP ----------------

__global__ __launch_bounds__(256, 4) void k_edge_l1(
    const int* __restrict__ srcs_s, const int* __restrict__ dsts_s,
    const float* __restrict__ Ps, const float* __restrict__ Pd,
    const unsigned short* __restrict__ wt,
    const float* __restrict__ pb1, const float* __restrict__ pb2,
    unsigned* __restrict__ epk)
{
    __shared__ unsigned short pEhi[EPB * LDK], pElo[EPB * LDK];
    __shared__ unsigned short pHhi[EPB * LDK], pHlo[EPB * LDK];

    const int t = threadIdx.x;
    const int lane = t & 63, ft = t >> 6;
    const int quad = lane >> 4, l15 = lane & 15;
    const int f0 = ft * 16 + quad * 4;
    const long eBase = (long)blockIdx.x * EPB;

    // load epk -> deinterleave -> pE
    {
        const int row = t >> 2, q = t & 3;
#pragma unroll
        for (int half = 0; half < 2; ++half) {
            const int lo = row * LDK + q * 8 + half * 32;
            const long go = (eBase + row) * HH + q * 8 + half * 32;
            union { unsigned u[8]; uint4 v[2]; } in;
            in.v[0] = *(const uint4*)(epk + go);
            in.v[1] = *(const uint4*)(epk + go + 4);
            union { unsigned short u[8]; uint4 v; } H, L;
#pragma unroll
            for (int i = 0; i < 8; ++i) {
                H.u[i] = (unsigned short)(in.u[i] >> 16);
                L.u[i] = (unsigned short)(in.u[i] & 0xFFFFu);
            }
            *(uint4*)(pEhi + lo) = H.v;
            *(uint4*)(pElo + lo) = L.v;
        }
    }
    int srcs[4], dsts[4];
#pragma unroll
    for (int et = 0; et < 4; ++et) {
        const long p = eBase + et * 16 + l15;
        srcs[et] = srcs_s[p];
        dsts[et] = dsts_s[p];
    }
    __syncthreads();

    f32x4 acc[4];

    // t1 = relu(e1 @ W1e + Ps[src] + Pd[dst] + pb1) -> pH
    {
        short8 w[2][2];
        load_wf(wt + S_W1E1 * 8192, ft, l15, quad, w);
        set_zero(acc);
        gemm_planes(pEhi, pElo, w, l15, quad, acc);
        const float4 b4 = *(const float4*)(pb1 + f0);
#pragma unroll
        for (int et = 0; et < 4; ++et) {
            const float4 ps = *(const float4*)(Ps + (size_t)srcs[et] * HH + f0);
            const float4 pd = *(const float4*)(Pd + (size_t)dsts[et] * HH + f0);
            acc[et][0] = fmaxf(acc[et][0] + ps.x + pd.x + b4.x, 0.f);
            acc[et][1] = fmaxf(acc[et][1] + ps.y + pd.y + b4.y, 0.f);
            acc[et][2] = fmaxf(acc[et][2] + ps.z + pd.z + b4.z, 0.f);
            acc[et][3] = fmaxf(acc[et][3] + ps.w + pd.w + b4.w, 0.f);
        }
        store_split_planes(pHhi, pHlo, acc, l15, f0);
    }
    __syncthreads();

    // e2 = e1(pE residual, own cells) + t1 @ W2e + pb2 -> pE
    {
        short8 w[2][2];
        load_wf(wt + S_W2E1 * 8192, ft, l15, quad, w);
        set_zero(acc);
        gemm_planes(pHhi, pHlo, w, l15, quad, acc);
        const float4 b4 = *(const float4*)(pb2 + f0);
#pragma unroll
        for (int et = 0; et < 4; ++et) {
            const int e = et * 16 + l15;
            const short4v hv = *(const short4v*)(pEhi + e * LDK + f0);
            const short4v lv = *(const short4v*)(pElo + e * LDK + f0);
            acc[et][0] += bf2f((unsigned short)hv[0]) + bf2f((unsigned short)lv[0]) + b4.x;
            acc[et][1] += bf2f((unsigned short)hv[1]) + bf2f((unsigned short)lv[1]) + b4.y;
            acc[et][2] += bf2f((unsigned short)hv[2]) + bf2f((unsigned short)lv[2]) + b4.z;
            acc[et][3] += bf2f((unsigned short)hv[3]) + bf2f((unsigned short)lv[3]) + b4.w;
        }
        store_split_planes(pEhi, pElo, acc, l15, f0);   // own cells, same thread
    }
    __syncthreads();

    // pack pE -> epk
    {
        const int row = t >> 2, q = t & 3;
#pragma unroll
        for (int half = 0; half < 2; ++half) {
            const int lo = row * LDK + q * 8 + half * 32;
            const long go = (eBase + row) * HH + q * 8 + half * 32;
            union { unsigned short u[8]; uint4 v; } H, L;
            H.v = *(const uint4*)(pEhi + lo);
            L.v = *(const uint4*)(pElo + lo);
            union { unsigned u[8]; uint4 v[2]; } o;
#pragma unroll
            for (int i = 0; i < 8; ++i) o.u[i] = ((unsigned)H.u[i] << 16) | L.u[i];
            *(uint4*)(epk + go) = o.v[0];
            *(uint4*)(epk + go + 4) = o.v[1];
        }
    }
}

// ---------------- K3: fused agg + node update l0 + layer-1 projections ----------------

__global__ __launch_bounds__(256, 4) void k_node_l0(
    float* __restrict__ x_h,
    const unsigned* __restrict__ off, const unsigned* __restrict__ epk,
    const unsigned short* __restrict__ wt,
    const float* __restrict__ nb1, const float* __restrict__ nb2,
    float* __restrict__ Ps, float* __restrict__ Pd)
{
    __shared__ unsigned short pXhi[EPB * LDK], pXlo[EPB * LDK];
    __shared__ unsigned short pAhi[EPB * LDK], pAlo[EPB * LDK];

    const int t = threadIdx.x;
    const int lane = t & 63, ft = t >> 6;
    const int quad = lane >> 4, l15 = lane & 15;
    const int f0 = ft * 16 + quad * 4;
    const int nodeBase = blockIdx.x * 64;
    const int nValid = min(64, NN - nodeBase);

    stage_split64(pXhi, pXlo, x_h, nodeBase, t, nValid);
    agg_to_planes(off, epk, pAhi, pAlo, nodeBase, t);   // streaming (sorted rows)
    __syncthreads();

    f32x4 acc[4];

    // t1 = relu(x_h @ W1x + agg @ W1a + nb1)
    {
        short8 w[2][2];
        load_wf(wt + S_W1NX0 * 8192, ft, l15, quad, w);
        set_bias(acc, nb1, f0);
        gemm_planes(pXhi, pXlo, w, l15, quad, acc);
        load_wf(wt + S_W1NA0 * 8192, ft, l15, quad, w);
        gemm_planes(pAhi, pAlo, w, l15, quad, acc);
        relu4(acc);
    }
    __syncthreads();                                // pA reads complete
    store_split_planes(pAhi, pAlo, acc, l15, f0);   // t1 -> pA
    __syncthreads();

    // x_h1 = x_h(planes) + t1 @ W2n + nb2 -> global + pX
    {
        short8 w[2][2];
        load_wf(wt + S_W2N0 * 8192, ft, l15, quad, w);
        set_bias(acc, nb2, f0);
        gemm_planes(pAhi, pAlo, w, l15, quad, acc);
#pragma unroll
        for (int et = 0; et < 4; ++et) {
            const int r = et * 16 + l15;
            const short4v hv = *(const short4v*)(pXhi + r * LDK + f0);
            const short4v lv = *(const short4v*)(pXlo + r * LDK + f0);
            acc[et][0] += bf2f((unsigned short)hv[0]) + bf2f((unsigned short)lv[0]);
            acc[et][1] += bf2f((unsigned short)hv[1]) + bf2f((unsigned short)lv[1]);
            acc[et][2] += bf2f((unsigned short)hv[2]) + bf2f((unsigned short)lv[2]);
            acc[et][3] += bf2f((unsigned short)hv[3]) + bf2f((unsigned short)lv[3]);
            if (r < nValid) {
                float4 v = make_float4(acc[et][0], acc[et][1], acc[et][2], acc[et][3]);
                *(float4*)(x_h + (size_t)(nodeBase + r) * HH + f0) = v;
            }
        }
        store_split_planes(pXhi, pXlo, acc, l15, f0);   // own cells, reads above done
    }
    __syncthreads();

    // Ps1 = x_h1 @ W1s(l1)
    {
        short8 w[2][2];
        load_wf(wt + S_W1S1 * 8192, ft, l15, quad, w);
        set_zero(acc);
        gemm_planes(pXhi, pXlo, w, l15, quad, acc);
#pragma unroll
        for (int et = 0; et < 4; ++et) {
            const int r = et * 16 + l15;
            if (r < nValid) {
                float4 v = make_float4(acc[et][0], acc[et][1], acc[et][2], acc[et][3]);
                *(float4*)(Ps + (size_t)(nodeBase + r) * HH + f0) = v;
            }
        }
    }
    // Pd1 = x_h1 @ W1d(l1)
    {
        short8 w[2][2];
        load_wf(wt + S_W1D1 * 8192, ft, l15, quad, w);
        set_zero(acc);
        gemm_planes(pXhi, pXlo, w, l15, quad, acc);
#pragma unroll
        for (int et = 0; et < 4; ++et) {
            const int r = et * 16 + l15;
            if (r < nValid) {
                float4 v = make_float4(acc[et][0], acc[et][1], acc[et][2], acc[et][3]);
                *(float4*)(Pd + (size_t)(nodeBase + r) * HH + f0) = v;
            }
        }
    }
}

// ---------------- K5: fused agg + node update l1 + decoder ----------------

__global__ __launch_bounds__(256, 4) void k_node_l1_dec(
    const float* __restrict__ x_h,
    const unsigned* __restrict__ off, const unsigned* __restrict__ epk,
    const unsigned short* __restrict__ wt,
    const float* __restrict__ nb1, const float* __restrict__ nb2,
    const float* __restrict__ db1, const float* __restrict__ dw2,
    const float* __restrict__ db2, float* __restrict__ out)
{
    __shared__ unsigned short pXhi[EPB * LDK], pXlo[EPB * LDK];
    __shared__ unsigned short pAhi[EPB * LDK], pAlo[EPB * LDK];
    __shared__ float sW2[64 * 6];

    const int t = threadIdx.x;
    const int lane = t & 63, ft = t >> 6;
    const int quad = lane >> 4, l15 = lane & 15;
    const int f0 = ft * 16 + quad * 4;
    const int nodeBase = blockIdx.x * 64;
    const int nValid = min(64, NN - nodeBase);

    stage_split64(pXhi, pXlo, x_h, nodeBase, t, nValid);
    agg_to_planes(off, epk, pAhi, pAlo, nodeBase, t);
    if (t < 192) {
        sW2[t] = dw2[t];
        sW2[t + 192] = dw2[t + 192];
    }
    __syncthreads();

    f32x4 acc[4];

    // t1 = relu(x_h @ W1x + agg @ W1a + nb1)
    {
        short8 w[2][2];
        load_wf(wt + S_W1NX1 * 8192, ft, l15, quad, w);
        set_bias(acc, nb1, f0);
        gemm_planes(pXhi, pXlo, w, l15, quad, acc);
        load_wf(wt + S_W1NA1 * 8192, ft, l15, quad, w);
        gemm_planes(pAhi, pAlo, w, l15, quad, acc);
        relu4(acc);
    }
    __syncthreads();
    store_split_planes(pAhi, pAlo, acc, l15, f0);   // t1 -> pA
    __syncthreads();

    // x_h2 = x_h(planes) + t1 @ W2n + nb2 -> pX
    {
        short8 w[2][2];
        load_wf(wt + S_W2N1 * 8192, ft, l15, quad, w);
        set_bias(acc, nb2, f0);
        gemm_planes(pAhi, pAlo, w, l15, quad, acc);
#pragma unroll
        for (int et = 0; et < 4; ++et) {
            const int r = et * 16 + l15;
            const short4v hv = *(const short4v*)(pXhi + r * LDK + f0);
            const short4v lv = *(const short4v*)(pXlo + r * LDK + f0);
            acc[et][0] += bf2f((unsigned short)hv[0]) + bf2f((unsigned short)lv[0]);
            acc[et][1] += bf2f((unsigned short)hv[1]) + bf2f((unsigned short)lv[1]);
            acc[et][2] += bf2f((unsigned short)hv[2]) + bf2f((unsigned short)lv[2]);
            acc[et][3] += bf2f((unsigned short)hv[3]) + bf2f((unsigned short)lv[3]);
        }
        store_split_planes(pXhi, pXlo, acc, l15, f0);
    }
    __syncthreads();

    // d1 = relu(x_h2 @ dec_w1 + db1) -> pA
    {
        short8 w[2][2];
        load_wf(wt + S_DW1 * 8192, ft, l15, quad, w);
        set_bias(acc, db1, f0);
        gemm_planes(pXhi, pXlo, w, l15, quad, acc);
        relu4(acc);
        store_split_planes(pAhi, pAlo, acc, l15, f0);
    }
    __syncthreads();

    // out = d1 @ dec_w2 + db2  (64 nodes x 6)
    if (t < 64 && t < nValid) {
        float o[6];
#pragma unroll
        for (int c = 0; c < 6; ++c) o[c] = db2[c];
#pragma unroll 8
        for (int k = 0; k < 64; ++k) {
            const float a = bf2f(pAhi[t * LDK + k]) + bf2f(pAlo[t * LDK + k]);
#pragma unroll
            for (int c = 0; c < 6; ++c) o[c] = fmaf(a, sW2[k * 6 + c], o[c]);
        }
        float* op = out + (size_t)(nodeBase + t) * 6;
#pragma unroll
        for (int c = 0; c < 6; ++c) op[c] = o[c];
    }
}

// ---------------- launcher ----------------

extern "C" void kernel_launch(void* const* d_in, const int* in_sizes, int n_in,
                              void* d_out, int out_size, void* d_ws, size_t ws_size,
                              hipStream_t stream) {
    const float* x        = (const float*)d_in[0];
    const float* eattr    = (const float*)d_in[1];
    const int*   eidx     = (const int*)d_in[2];
    const float* enc_n_w1 = (const float*)d_in[3];
    const float* enc_n_b1 = (const float*)d_in[4];
    const float* enc_n_w2 = (const float*)d_in[5];
    const float* enc_n_b2 = (const float*)d_in[6];
    const float* enc_e_w1 = (const float*)d_in[7];
    const float* enc_e_b1 = (const float*)d_in[8];
    const float* enc_e_w2 = (const float*)d_in[9];
    const float* enc_e_b2 = (const float*)d_in[10];
    const float* pe_w1    = (const float*)d_in[11];  // [2,192,64]
    const float* pe_b1    = (const float*)d_in[12];  // [2,64]
    const float* pe_w2    = (const float*)d_in[13];  // [2,64,64]
    const float* pe_b2    = (const float*)d_in[14];  // [2,64]
    const float* pn_w1    = (const float*)d_in[15];  // [2,128,64]
    const float* pn_b1    = (const float*)d_in[16];
    const float* pn_w2    = (const float*)d_in[17];  // [2,64,64]
    const float* pn_b2    = (const float*)d_in[18];
    const float* dw1      = (const float*)d_in[19];
    const float* db1      = (const float*)d_in[20];
    const float* dw2      = (const float*)d_in[21];
    const float* db2      = (const float*)d_in[22];
    float* out = (float*)d_out;

    // ws: x_h | Ps | Pd | epk | off | deg | csr | srcs_s | dsts_s | wt  (~253.5MB)
    const size_t NNHH = (size_t)NN * HH;
    float* ws  = (float*)d_ws;
    float* x_h = ws;
    float* Ps  = ws + NNHH;
    float* Pd  = ws + 2 * NNHH;
    unsigned* epk = (unsigned*)(ws + 3 * NNHH);           // EE*HH uints
    unsigned* off = epk + (size_t)EE * HH;                // NN+1
    unsigned* deg = off + (NN + 1);                       // NN, reused as cursor
    int* csr    = (int*)(deg + NN);                       // EE
    int* srcs_s = csr + EE;                               // EE
    int* dsts_s = srcs_s + EE;                            // EE
    unsigned short* wt = (unsigned short*)(dsts_s + EE);  // WT_USHORTS

    const int edgeBlocks = EE / EPB;         // 12500
    const int nodeBlocks = (NN + 63) / 64;   // 782

    hipMemsetAsync(deg, 0, (size_t)NN * sizeof(unsigned), stream);

    k_setup<<<DEG_BLOCKS + CONV_BLOCKS, 256, 0, stream>>>(
        eidx, deg,
        enc_n_w1, enc_n_w2, enc_e_w1, enc_e_w2,
        pe_w1, pe_w2, pn_w1, pn_w2, dw1, wt);

    k_scan<<<1, 1024, 0, stream>>>(deg, off);

    k_fill_encode<<<FILL_BLOCKS + ENC_BLOCKS, 256, 0, stream>>>(
        eidx, deg, csr, srcs_s, dsts_s,
        x, wt, enc_n_b1, enc_n_b2, x_h, Ps, Pd);

    k_edge_l0<<<edgeBlocks, 256, 0, stream>>>(
        eattr, csr, srcs_s, dsts_s, Ps, Pd,
        enc_e_b1, enc_e_b2, wt, pe_b1, pe_b2, epk);

    k_node_l0<<<nodeBlocks, 256, 0, stream>>>(
        x_h, off, epk, wt, pn_b1, pn_b2, Ps, Pd);

    k_edge_l1<<<edgeBlocks, 256, 0, stream>>>(
        srcs_s, dsts_s, Ps, Pd, wt, pe_b1 + 64, pe_b2 + 64, epk);

    k_node_l1_dec<<<nodeBlocks, 256, 0, stream>>>(
        x_h, off, epk, wt, pn_b1 + 64, pn_b2 + 64,
        db1, dw2, db2, out);
}